// Round 1
// baseline (377.690 us; speedup 1.0000x reference)
//
#include <hip/hip_runtime.h>
#include <math.h>

#define N_NODES 30000
#define N_EDGES 150000
#define IN_F 16
#define H_F 32
#define C_F 10
// K = IN*H = 512 hidden units in the edge MLP; 513 piecewise-linear intervals.

// ---------------------------------------------------------------------------
// K0: zero the accumulator region of the workspace
// ---------------------------------------------------------------------------
__global__ void k0_zero(float* __restrict__ p, int n) {
    int i = blockIdx.x * blockDim.x + threadIdx.x;
    int stride = gridDim.x * blockDim.x;
    for (; i < n; i += stride) p[i] = 0.0f;
}

// ---------------------------------------------------------------------------
// K1: compute breakpoints t_k = -b1_k / W1_k and bitonic-sort (t, k) pairs.
// One block, 512 threads. w==0 entries get t=+3e38 (never crossed; delta=0).
// ---------------------------------------------------------------------------
__global__ void k1_sort(const float* __restrict__ W1, const float* __restrict__ b1,
                        float* __restrict__ tsort, int* __restrict__ ksort) {
    __shared__ float st[512];
    __shared__ int   sk[512];
    int tid = threadIdx.x;
    float w = W1[tid], b = b1[tid];
    float t = (w != 0.0f) ? (-b / w) : 3.0e38f;
    st[tid] = t; sk[tid] = tid;
    __syncthreads();
    for (int ksz = 2; ksz <= 512; ksz <<= 1) {
        for (int jj = ksz >> 1; jj > 0; jj >>= 1) {
            int i = tid, ixj = i ^ jj;
            if (ixj > i) {
                bool up = ((i & ksz) == 0);
                float a1 = st[i], a2 = st[ixj];
                if ((a1 > a2) == up) {
                    st[i] = a2; st[ixj] = a1;
                    int tt = sk[i]; sk[i] = sk[ixj]; sk[ixj] = tt;
                }
            }
            __syncthreads();
        }
    }
    tsort[tid] = st[tid];
    ksort[tid] = sk[tid];
}

// ---------------------------------------------------------------------------
// K2a: base active set at a -> -inf:  {k: w<0} U {k: w==0 && b>0}
// baseA[j] = sum w_k*W2[k,j], baseB[j] = sum b_k*W2[k,j].  2 blocks x 256.
// ---------------------------------------------------------------------------
__global__ void k2a_base(const float* __restrict__ W1, const float* __restrict__ b1,
                         const float* __restrict__ W2,
                         float* __restrict__ baseA, float* __restrict__ baseB) {
    int j = blockIdx.x * blockDim.x + threadIdx.x;  // 0..511
    float ba = 0.0f, bb = 0.0f;
    for (int k = 0; k < 512; ++k) {
        float w = W1[k], b = b1[k];
        bool act = (w < 0.0f) || (w == 0.0f && b > 0.0f);
        if (act) {
            float w2 = W2[k * 512 + j];
            ba = fmaf(w, w2, ba);
            bb = fmaf(b, w2, bb);
        }
    }
    baseA[j] = ba;
    baseB[j] = bb;
}

// ---------------------------------------------------------------------------
// K2b: build A[513][512], B2[513][512] tables via prefix over sorted ranks.
// Crossing rank r upward toggles k_r: w>0 -> add (w,b)*W2row, w<0 -> subtract.
// Grid = 64 blocks: (mc = blockIdx&31 gives m-chunk of 16, jc = blockIdx>>5
// gives 256-wide j chunk). B2 rows have b2[j] folded in.
// ---------------------------------------------------------------------------
__global__ void k2b_tables(const float* __restrict__ W1, const float* __restrict__ b1,
                           const float* __restrict__ b2, const float* __restrict__ W2,
                           const int* __restrict__ ksort,
                           const float* __restrict__ baseA, const float* __restrict__ baseB,
                           float* __restrict__ A, float* __restrict__ B2t) {
    int mc = blockIdx.x & 31;
    int jc = blockIdx.x >> 5;
    int j = jc * 256 + threadIdx.x;
    float runA = baseA[j], runB = baseB[j];
    float bb2 = b2[j];
    int mstart = mc * 16;
    for (int r = 0; r < mstart; ++r) {
        int k = ksort[r];
        float w = W1[k], b = b1[k];
        float sgn = (w > 0.0f) ? 1.0f : ((w < 0.0f) ? -1.0f : 0.0f);
        float w2 = W2[k * 512 + j];
        runA = fmaf(sgn * w, w2, runA);
        runB = fmaf(sgn * b, w2, runB);
    }
    for (int s = 0; s < 16; ++s) {
        int m = mstart + s;
        A[m * 512 + j]   = runA;
        B2t[m * 512 + j] = runB + bb2;
        int k = ksort[m];
        float w = W1[k], b = b1[k];
        float sgn = (w > 0.0f) ? 1.0f : ((w < 0.0f) ? -1.0f : 0.0f);
        float w2 = W2[k * 512 + j];
        runA = fmaf(sgn * w, w2, runA);
        runB = fmaf(sgn * b, w2, runB);
    }
    if (mc == 31) {
        A[512 * 512 + j]   = runA;
        B2t[512 * 512 + j] = runB + bb2;
    }
}

// ---------------------------------------------------------------------------
// K3: per-edge message. 32 lanes per edge (o = lane). Binary-search interval m,
// msg[o] = a*(x_src . A_m[:,o]) + (x_src . B2_m[:,o]); atomic scatter to dst.
// ---------------------------------------------------------------------------
__global__ void k3_edges(const float* __restrict__ x, const float* __restrict__ ea,
                         const int* __restrict__ ei,
                         const float* __restrict__ A, const float* __restrict__ B2t,
                         const float* __restrict__ tsort,
                         float* __restrict__ summed, float* __restrict__ cntf) {
    __shared__ float ts[512];
    for (int i = threadIdx.x; i < 512; i += blockDim.x) ts[i] = tsort[i];
    __syncthreads();
    int gid = blockIdx.x * blockDim.x + threadIdx.x;
    int lane = gid & 31;
    int e = gid >> 5;
    if (e >= N_EDGES) return;
    float a = ea[e];
    int s = ei[e], d = ei[N_EDGES + e];
    // m = #{t_r < a}
    int lo = 0, hi = 512;
    while (lo < hi) {
        int mid = (lo + hi) >> 1;
        if (ts[mid] < a) lo = mid + 1; else hi = mid;
    }
    int m = lo;
    float xv = (lane < 16) ? x[s * 16 + lane] : 0.0f;
    const float* Ar = A   + m * 512;
    const float* Br = B2t + m * 512;
    float xa = 0.0f, xb = 0.0f;
#pragma unroll
    for (int i = 0; i < 16; ++i) {
        float xi = __shfl(xv, i, 32);
        xa = fmaf(xi, Ar[i * 32 + lane], xa);
        xb = fmaf(xi, Br[i * 32 + lane], xb);
    }
    float msg = fmaf(a, xa, xb);
    atomicAdd(&summed[d * 32 + lane], msg);
    if (lane == 0) atomicAdd(&cntf[d], 1.0f);
}

// ---------------------------------------------------------------------------
// K4: per-node: aggr = summed/max(cnt,1); h1 = relu(aggr + x@root + bias1);
// xw = h1@Wg; dinv = rsqrt(indeg + 1).
// ---------------------------------------------------------------------------
__global__ void k4_nodes(const float* __restrict__ x, const float* __restrict__ summed,
                         const float* __restrict__ cntf,
                         const float* __restrict__ root, const float* __restrict__ bias1,
                         const float* __restrict__ Wg,
                         float* __restrict__ xw, float* __restrict__ dinv) {
    __shared__ float sroot[512], sb1[32], swg[320];
    for (int i = threadIdx.x; i < 512; i += blockDim.x) sroot[i] = root[i];
    for (int i = threadIdx.x; i < 32; i += blockDim.x) sb1[i] = bias1[i];
    for (int i = threadIdx.x; i < 320; i += blockDim.x) swg[i] = Wg[i];
    __syncthreads();
    int n = blockIdx.x * blockDim.x + threadIdx.x;
    if (n >= N_NODES) return;
    float c = cntf[n];
    float inv = 1.0f / fmaxf(c, 1.0f);
    float xr[16];
#pragma unroll
    for (int i = 0; i < 16; ++i) xr[i] = x[n * 16 + i];
    float acc[10];
#pragma unroll
    for (int cc = 0; cc < 10; ++cc) acc[cc] = 0.0f;
#pragma unroll
    for (int o = 0; o < 32; ++o) {
        float h = summed[n * 32 + o] * inv + sb1[o];
#pragma unroll
        for (int i = 0; i < 16; ++i) h = fmaf(xr[i], sroot[i * 32 + o], h);
        h = fmaxf(h, 0.0f);
#pragma unroll
        for (int cc = 0; cc < 10; ++cc) acc[cc] = fmaf(h, swg[o * 10 + cc], acc[cc]);
    }
#pragma unroll
    for (int cc = 0; cc < 10; ++cc) xw[n * 10 + cc] = acc[cc];
    dinv[n] = rsqrtf(c + 1.0f);
}

// ---------------------------------------------------------------------------
// K5: GCN edge scatter: outacc[dst] += xw[src] * dinv[src] * dinv[dst]
// ---------------------------------------------------------------------------
__global__ void k5_gcn(const int* __restrict__ ei, const float* __restrict__ xw,
                       const float* __restrict__ dinv, float* __restrict__ outacc) {
    int e = blockIdx.x * blockDim.x + threadIdx.x;
    if (e >= N_EDGES) return;
    int s = ei[e], d = ei[N_EDGES + e];
    float nf = dinv[s] * dinv[d];
#pragma unroll
    for (int c = 0; c < 10; ++c)
        atomicAdd(&outacc[d * 10 + c], xw[s * 10 + c] * nf);
}

// ---------------------------------------------------------------------------
// K6: self-loop + bg + log_softmax -> d_out
// ---------------------------------------------------------------------------
__global__ void k6_final(const float* __restrict__ outacc, const float* __restrict__ xw,
                         const float* __restrict__ dinv, const float* __restrict__ bg,
                         float* __restrict__ out) {
    __shared__ float sbg[16];
    if (threadIdx.x < 10) sbg[threadIdx.x] = bg[threadIdx.x];
    __syncthreads();
    int n = blockIdx.x * blockDim.x + threadIdx.x;
    if (n >= N_NODES) return;
    float d2 = dinv[n] * dinv[n];
    float v[10];
    float mx = -1e30f;
#pragma unroll
    for (int c = 0; c < 10; ++c) {
        v[c] = outacc[n * 10 + c] + xw[n * 10 + c] * d2 + sbg[c];
        mx = fmaxf(mx, v[c]);
    }
    float se = 0.0f;
#pragma unroll
    for (int c = 0; c < 10; ++c) se += expf(v[c] - mx);
    float lse = logf(se) + mx;
#pragma unroll
    for (int c = 0; c < 10; ++c) out[n * 10 + c] = v[c] - lse;
}

// ---------------------------------------------------------------------------
extern "C" void kernel_launch(void* const* d_in, const int* in_sizes, int n_in,
                              void* d_out, int out_size, void* d_ws, size_t ws_size,
                              hipStream_t stream) {
    const float* x     = (const float*)d_in[0];
    const float* ea    = (const float*)d_in[1];
    const float* W1    = (const float*)d_in[2];
    const float* b1    = (const float*)d_in[3];
    const float* W2    = (const float*)d_in[4];
    const float* b2    = (const float*)d_in[5];
    const float* root  = (const float*)d_in[6];
    const float* bias1 = (const float*)d_in[7];
    const float* Wg    = (const float*)d_in[8];
    const float* bg    = (const float*)d_in[9];
    const int*   ei    = (const int*)d_in[10];
    float* out = (float*)d_out;

    // workspace layout (floats):
    //   A[513*512] | B2[513*512] | tsort[512] | ksort[512] | baseA[512] | baseB[512]
    //   | summed[N*32] | cntf[N] | outacc[N*10]  (<- zeroed region, contiguous)
    //   | xw[N*10] | dinv[N]
    float* A      = (float*)d_ws;
    float* B2t    = A + 513 * 512;
    float* tsort  = B2t + 513 * 512;
    int*   ksort  = (int*)(tsort + 512);
    float* baseA  = (float*)(ksort + 512);
    float* baseB  = baseA + 512;
    float* summed = baseB + 512;
    float* cntf   = summed + N_NODES * 32;
    float* outacc = cntf + N_NODES;
    float* xw     = outacc + N_NODES * 10;
    float* dinv   = xw + N_NODES * 10;

    k0_zero<<<1024, 256, 0, stream>>>(summed, N_NODES * 43);
    k1_sort<<<1, 512, 0, stream>>>(W1, b1, tsort, ksort);
    k2a_base<<<2, 256, 0, stream>>>(W1, b1, W2, baseA, baseB);
    k2b_tables<<<64, 256, 0, stream>>>(W1, b1, b2, W2, ksort, baseA, baseB, A, B2t);
    k3_edges<<<(N_EDGES * 32 + 255) / 256, 256, 0, stream>>>(x, ea, ei, A, B2t, tsort,
                                                             summed, cntf);
    k4_nodes<<<(N_NODES + 255) / 256, 256, 0, stream>>>(x, summed, cntf, root, bias1,
                                                        Wg, xw, dinv);
    k5_gcn<<<(N_EDGES + 255) / 256, 256, 0, stream>>>(ei, xw, dinv, outacc);
    k6_final<<<(N_NODES + 255) / 256, 256, 0, stream>>>(outacc, xw, dinv, bg, out);
}

// Round 2
// 175.442 us; speedup vs baseline: 2.1528x; 2.1528x over previous
//
#include <hip/hip_runtime.h>
#include <math.h>

#define N_NODES 30000
#define N_EDGES 150000
#define IN_F 16
#define H_F 32
#define C_F 10
// K = IN*H = 512 hidden units in the edge MLP; 513 piecewise-linear intervals.

// ---------------------------------------------------------------------------
// K0: zero the accumulator region of the workspace
// ---------------------------------------------------------------------------
__global__ void k0_zero(float* __restrict__ p, int n) {
    int i = blockIdx.x * blockDim.x + threadIdx.x;
    int stride = gridDim.x * blockDim.x;
    for (; i < n; i += stride) p[i] = 0.0f;
}

// ---------------------------------------------------------------------------
// K1: compute breakpoints t_k = -b1_k / W1_k and bitonic-sort (t, k) pairs.
// One block, 512 threads. w==0 entries get t=+3e38 (never crossed; delta=0).
// ---------------------------------------------------------------------------
__global__ void k1_sort(const float* __restrict__ W1, const float* __restrict__ b1,
                        float* __restrict__ tsort, int* __restrict__ ksort) {
    __shared__ float st[512];
    __shared__ int   sk[512];
    int tid = threadIdx.x;
    float w = W1[tid], b = b1[tid];
    float t = (w != 0.0f) ? (-b / w) : 3.0e38f;
    st[tid] = t; sk[tid] = tid;
    __syncthreads();
    for (int ksz = 2; ksz <= 512; ksz <<= 1) {
        for (int jj = ksz >> 1; jj > 0; jj >>= 1) {
            int i = tid, ixj = i ^ jj;
            if (ixj > i) {
                bool up = ((i & ksz) == 0);
                float a1 = st[i], a2 = st[ixj];
                if ((a1 > a2) == up) {
                    st[i] = a2; st[ixj] = a1;
                    int tt = sk[i]; sk[i] = sk[ixj]; sk[ixj] = tt;
                }
            }
            __syncthreads();
        }
    }
    tsort[tid] = st[tid];
    ksort[tid] = sk[tid];
}

// ---------------------------------------------------------------------------
// P1: per-chunk partial sums. 32 chunks of 16 ranks. For chunk c, col j:
//   PbA/PbB: masked base-set partials over k in [16c,16c+16) (natural order)
//   SA/SB:   sorted-rank chunk sums (sgn*w, sgn*b weighted W2 rows)
// Grid 64 = 32 chunks x 2 j-chunks of 256.
// ---------------------------------------------------------------------------
__global__ void p1_chunks(const float* __restrict__ W1, const float* __restrict__ b1,
                          const float* __restrict__ W2, const int* __restrict__ ksort,
                          float* __restrict__ PbA, float* __restrict__ PbB,
                          float* __restrict__ SA, float* __restrict__ SB) {
    int c = blockIdx.x & 31;
    int jc = blockIdx.x >> 5;
    int j = jc * 256 + threadIdx.x;
    float ba = 0.0f, bb = 0.0f, sa = 0.0f, sb = 0.0f;
#pragma unroll 4
    for (int s = 0; s < 16; ++s) {
        int k = c * 16 + s;
        float w = W1[k], b = b1[k];
        bool act = (w < 0.0f) || (w == 0.0f && b > 0.0f);
        if (act) {
            float w2 = W2[k * 512 + j];
            ba = fmaf(w, w2, ba);
            bb = fmaf(b, w2, bb);
        }
        int kr = ksort[c * 16 + s];
        float wr = W1[kr], br = b1[kr];
        float sgn = (wr > 0.0f) ? 1.0f : ((wr < 0.0f) ? -1.0f : 0.0f);
        float w2r = W2[kr * 512 + j];
        sa = fmaf(sgn * wr, w2r, sa);
        sb = fmaf(sgn * br, w2r, sb);
    }
    PbA[c * 512 + j] = ba; PbB[c * 512 + j] = bb;
    SA[c * 512 + j] = sa;  SB[c * 512 + j] = sb;
}

// ---------------------------------------------------------------------------
// P2: per-column scan over the 32 chunks. base = sum of masked partials;
// then exclusive prefix of SA/SB (+base) written back over PbA/PbB.
// 2 blocks x 256.
// ---------------------------------------------------------------------------
__global__ void p2_prefix(float* __restrict__ PbA, float* __restrict__ PbB,
                          const float* __restrict__ SA, const float* __restrict__ SB) {
    int j = blockIdx.x * 256 + threadIdx.x;
    float bA = 0.0f, bB = 0.0f;
#pragma unroll
    for (int c = 0; c < 32; ++c) { bA += PbA[c * 512 + j]; bB += PbB[c * 512 + j]; }
    float rA = bA, rB = bB;
#pragma unroll
    for (int c = 0; c < 32; ++c) {
        float sA = SA[c * 512 + j], sB = SB[c * 512 + j];
        PbA[c * 512 + j] = rA;
        PbB[c * 512 + j] = rB;
        rA += sA; rB += sB;
    }
}

// ---------------------------------------------------------------------------
// P3: emit A[513][512], B2[513][512]. Chunk c starts from scanned prefix
// PA[c][j] and walks its 16 ranks. Chunk 31 also emits row 512.
// Grid 64 = 32 chunks x 2 j-chunks.
// ---------------------------------------------------------------------------
__global__ void p3_emit(const float* __restrict__ W1, const float* __restrict__ b1,
                        const float* __restrict__ b2, const float* __restrict__ W2,
                        const int* __restrict__ ksort,
                        const float* __restrict__ PA, const float* __restrict__ PB,
                        float* __restrict__ A, float* __restrict__ B2t) {
    int c = blockIdx.x & 31;
    int jc = blockIdx.x >> 5;
    int j = jc * 256 + threadIdx.x;
    float runA = PA[c * 512 + j], runB = PB[c * 512 + j];
    float bb2 = b2[j];
#pragma unroll 4
    for (int s = 0; s < 16; ++s) {
        int m = c * 16 + s;
        A[m * 512 + j]   = runA;
        B2t[m * 512 + j] = runB + bb2;
        int k = ksort[m];
        float w = W1[k], b = b1[k];
        float sgn = (w > 0.0f) ? 1.0f : ((w < 0.0f) ? -1.0f : 0.0f);
        float w2 = W2[k * 512 + j];
        runA = fmaf(sgn * w, w2, runA);
        runB = fmaf(sgn * b, w2, runB);
    }
    if (c == 31) {
        A[512 * 512 + j]   = runA;
        B2t[512 * 512 + j] = runB + bb2;
    }
}

// ---------------------------------------------------------------------------
// K3: per-edge message. 32 lanes per edge (o = lane). Binary-search interval m,
// msg[o] = a*(x_src . A_m[:,o]) + (x_src . B2_m[:,o]); atomic scatter to dst.
// ---------------------------------------------------------------------------
__global__ void k3_edges(const float* __restrict__ x, const float* __restrict__ ea,
                         const int* __restrict__ ei,
                         const float* __restrict__ A, const float* __restrict__ B2t,
                         const float* __restrict__ tsort,
                         float* __restrict__ summed, float* __restrict__ cntf) {
    __shared__ float ts[512];
    for (int i = threadIdx.x; i < 512; i += blockDim.x) ts[i] = tsort[i];
    __syncthreads();
    int gid = blockIdx.x * blockDim.x + threadIdx.x;
    int lane = gid & 31;
    int e = gid >> 5;
    if (e >= N_EDGES) return;
    float a = ea[e];
    int s = ei[e], d = ei[N_EDGES + e];
    // m = #{t_r < a}
    int lo = 0, hi = 512;
    while (lo < hi) {
        int mid = (lo + hi) >> 1;
        if (ts[mid] < a) lo = mid + 1; else hi = mid;
    }
    int m = lo;
    float xv = (lane < 16) ? x[s * 16 + lane] : 0.0f;
    const float* Ar = A   + m * 512;
    const float* Br = B2t + m * 512;
    float xa = 0.0f, xb = 0.0f;
#pragma unroll
    for (int i = 0; i < 16; ++i) {
        float xi = __shfl(xv, i, 32);
        xa = fmaf(xi, Ar[i * 32 + lane], xa);
        xb = fmaf(xi, Br[i * 32 + lane], xb);
    }
    float msg = fmaf(a, xa, xb);
    atomicAdd(&summed[d * 32 + lane], msg);
    if (lane == 0) atomicAdd(&cntf[d], 1.0f);
}

// ---------------------------------------------------------------------------
// K4: per-node: aggr = summed/max(cnt,1); h1 = relu(aggr + x@root + bias1);
// xw = h1@Wg; dinv = rsqrt(indeg + 1).
// ---------------------------------------------------------------------------
__global__ void k4_nodes(const float* __restrict__ x, const float* __restrict__ summed,
                         const float* __restrict__ cntf,
                         const float* __restrict__ root, const float* __restrict__ bias1,
                         const float* __restrict__ Wg,
                         float* __restrict__ xw, float* __restrict__ dinv) {
    __shared__ float sroot[512], sb1[32], swg[320];
    for (int i = threadIdx.x; i < 512; i += blockDim.x) sroot[i] = root[i];
    for (int i = threadIdx.x; i < 32; i += blockDim.x) sb1[i] = bias1[i];
    for (int i = threadIdx.x; i < 320; i += blockDim.x) swg[i] = Wg[i];
    __syncthreads();
    int n = blockIdx.x * blockDim.x + threadIdx.x;
    if (n >= N_NODES) return;
    float c = cntf[n];
    float inv = 1.0f / fmaxf(c, 1.0f);
    float xr[16];
#pragma unroll
    for (int i = 0; i < 16; ++i) xr[i] = x[n * 16 + i];
    float acc[10];
#pragma unroll
    for (int cc = 0; cc < 10; ++cc) acc[cc] = 0.0f;
#pragma unroll
    for (int o = 0; o < 32; ++o) {
        float h = summed[n * 32 + o] * inv + sb1[o];
#pragma unroll
        for (int i = 0; i < 16; ++i) h = fmaf(xr[i], sroot[i * 32 + o], h);
        h = fmaxf(h, 0.0f);
#pragma unroll
        for (int cc = 0; cc < 10; ++cc) acc[cc] = fmaf(h, swg[o * 10 + cc], acc[cc]);
    }
#pragma unroll
    for (int cc = 0; cc < 10; ++cc) xw[n * 10 + cc] = acc[cc];
    dinv[n] = rsqrtf(c + 1.0f);
}

// ---------------------------------------------------------------------------
// K5: GCN edge scatter: outacc[dst] += xw[src] * dinv[src] * dinv[dst]
// ---------------------------------------------------------------------------
__global__ void k5_gcn(const int* __restrict__ ei, const float* __restrict__ xw,
                       const float* __restrict__ dinv, float* __restrict__ outacc) {
    int e = blockIdx.x * blockDim.x + threadIdx.x;
    if (e >= N_EDGES) return;
    int s = ei[e], d = ei[N_EDGES + e];
    float nf = dinv[s] * dinv[d];
#pragma unroll
    for (int c = 0; c < 10; ++c)
        atomicAdd(&outacc[d * 10 + c], xw[s * 10 + c] * nf);
}

// ---------------------------------------------------------------------------
// K6: self-loop + bg + log_softmax -> d_out
// ---------------------------------------------------------------------------
__global__ void k6_final(const float* __restrict__ outacc, const float* __restrict__ xw,
                         const float* __restrict__ dinv, const float* __restrict__ bg,
                         float* __restrict__ out) {
    __shared__ float sbg[16];
    if (threadIdx.x < 10) sbg[threadIdx.x] = bg[threadIdx.x];
    __syncthreads();
    int n = blockIdx.x * blockDim.x + threadIdx.x;
    if (n >= N_NODES) return;
    float d2 = dinv[n] * dinv[n];
    float v[10];
    float mx = -1e30f;
#pragma unroll
    for (int c = 0; c < 10; ++c) {
        v[c] = outacc[n * 10 + c] + xw[n * 10 + c] * d2 + sbg[c];
        mx = fmaxf(mx, v[c]);
    }
    float se = 0.0f;
#pragma unroll
    for (int c = 0; c < 10; ++c) se += expf(v[c] - mx);
    float lse = logf(se) + mx;
#pragma unroll
    for (int c = 0; c < 10; ++c) out[n * 10 + c] = v[c] - lse;
}

// ---------------------------------------------------------------------------
extern "C" void kernel_launch(void* const* d_in, const int* in_sizes, int n_in,
                              void* d_out, int out_size, void* d_ws, size_t ws_size,
                              hipStream_t stream) {
    const float* x     = (const float*)d_in[0];
    const float* ea    = (const float*)d_in[1];
    const float* W1    = (const float*)d_in[2];
    const float* b1    = (const float*)d_in[3];
    const float* W2    = (const float*)d_in[4];
    const float* b2    = (const float*)d_in[5];
    const float* root  = (const float*)d_in[6];
    const float* bias1 = (const float*)d_in[7];
    const float* Wg    = (const float*)d_in[8];
    const float* bg    = (const float*)d_in[9];
    const int*   ei    = (const int*)d_in[10];
    float* out = (float*)d_out;

    // workspace layout (floats):
    //   A[513*512] | B2[513*512] | tsort[512] | ksort[512]
    //   | summed[N*32] | cntf[N] | outacc[N*10]  (<- zeroed region, contiguous)
    //   | xw[N*10] | dinv[N]
    //   | PbA[32*512] | PbB[32*512] | SA[32*512] | SB[32*512]
    float* A      = (float*)d_ws;
    float* B2t    = A + 513 * 512;
    float* tsort  = B2t + 513 * 512;
    int*   ksort  = (int*)(tsort + 512);
    float* summed = (float*)(ksort + 512);
    float* cntf   = summed + N_NODES * 32;
    float* outacc = cntf + N_NODES;
    float* xw     = outacc + N_NODES * 10;
    float* dinv   = xw + N_NODES * 10;
    float* PbA    = dinv + N_NODES;
    float* PbB    = PbA + 32 * 512;
    float* SA     = PbB + 32 * 512;
    float* SB     = SA + 32 * 512;

    k0_zero<<<1024, 256, 0, stream>>>(summed, N_NODES * 43);
    k1_sort<<<1, 512, 0, stream>>>(W1, b1, tsort, ksort);
    p1_chunks<<<64, 256, 0, stream>>>(W1, b1, W2, ksort, PbA, PbB, SA, SB);
    p2_prefix<<<2, 256, 0, stream>>>(PbA, PbB, SA, SB);
    p3_emit<<<64, 256, 0, stream>>>(W1, b1, b2, W2, ksort, PbA, PbB, A, B2t);
    k3_edges<<<(N_EDGES * 32 + 255) / 256, 256, 0, stream>>>(x, ea, ei, A, B2t, tsort,
                                                             summed, cntf);
    k4_nodes<<<(N_NODES + 255) / 256, 256, 0, stream>>>(x, summed, cntf, root, bias1,
                                                        Wg, xw, dinv);
    k5_gcn<<<(N_EDGES + 255) / 256, 256, 0, stream>>>(ei, xw, dinv, outacc);
    k6_final<<<(N_NODES + 255) / 256, 256, 0, stream>>>(outacc, xw, dinv, bg, out);
}

// Round 3
// 156.323 us; speedup vs baseline: 2.4161x; 1.1223x over previous
//
#include <hip/hip_runtime.h>
#include <math.h>

#define N_NODES 30000
#define N_EDGES 150000
#define IN_F 16
#define H_F 32
#define C_F 10
// K = IN*H = 512 hidden units in the edge MLP; 513 piecewise-linear intervals.

// ---------------------------------------------------------------------------
// K0: zero a region of the workspace (summed[N*32] + deg[N], contiguous)
// ---------------------------------------------------------------------------
__global__ void k0_zero(float* __restrict__ p, int n) {
    int i = blockIdx.x * blockDim.x + threadIdx.x;
    int stride = gridDim.x * blockDim.x;
    for (; i < n; i += stride) p[i] = 0.0f;
}

// ---------------------------------------------------------------------------
// K1: compute breakpoints t_k = -b1_k / W1_k and bitonic-sort (t, k) pairs.
// One block, 512 threads. w==0 entries get t=+3e38 (never crossed; delta=0).
// ---------------------------------------------------------------------------
__global__ void k1_sort(const float* __restrict__ W1, const float* __restrict__ b1,
                        float* __restrict__ tsort, int* __restrict__ ksort) {
    __shared__ float st[512];
    __shared__ int   sk[512];
    int tid = threadIdx.x;
    float w = W1[tid], b = b1[tid];
    float t = (w != 0.0f) ? (-b / w) : 3.0e38f;
    st[tid] = t; sk[tid] = tid;
    __syncthreads();
    for (int ksz = 2; ksz <= 512; ksz <<= 1) {
        for (int jj = ksz >> 1; jj > 0; jj >>= 1) {
            int i = tid, ixj = i ^ jj;
            if (ixj > i) {
                bool up = ((i & ksz) == 0);
                float a1 = st[i], a2 = st[ixj];
                if ((a1 > a2) == up) {
                    st[i] = a2; st[ixj] = a1;
                    int tt = sk[i]; sk[i] = sk[ixj]; sk[ixj] = tt;
                }
            }
            __syncthreads();
        }
    }
    tsort[tid] = st[tid];
    ksort[tid] = sk[tid];
}

// ---------------------------------------------------------------------------
// CSR build: in-degree histogram -> single-block scan -> bucket fill
// ---------------------------------------------------------------------------
__global__ void kb1_deg(const int* __restrict__ ei, int* __restrict__ deg) {
    int e = blockIdx.x * blockDim.x + threadIdx.x;
    if (e < N_EDGES) atomicAdd(&deg[ei[N_EDGES + e]], 1);
}

// single block, 1024 threads, 30 elements each
__global__ void s_scan(const int* __restrict__ deg, int* __restrict__ offs,
                       int* __restrict__ cur) {
    __shared__ int part[1024];
    int t = threadIdx.x;
    int base = t * 30;
    int loc[30];
    int s = 0;
#pragma unroll
    for (int i = 0; i < 30; ++i) {
        int idx = base + i;
        int v = (idx < N_NODES) ? deg[idx] : 0;
        loc[i] = v;
        s += v;
    }
    part[t] = s;
    __syncthreads();
    for (int off = 1; off < 1024; off <<= 1) {
        int v = part[t];
        int add = (t >= off) ? part[t - off] : 0;
        __syncthreads();
        part[t] = v + add;
        __syncthreads();
    }
    int run = (t > 0) ? part[t - 1] : 0;
#pragma unroll
    for (int i = 0; i < 30; ++i) {
        int idx = base + i;
        if (idx < N_NODES) { offs[idx] = run; cur[idx] = run; }
        run += loc[i];
    }
    if (t == 1023) offs[N_NODES] = run;
}

__global__ void kb3_fill(const int* __restrict__ ei, int* __restrict__ cur,
                         int* __restrict__ ssrc) {
    int e = blockIdx.x * blockDim.x + threadIdx.x;
    if (e < N_EDGES) {
        int d = ei[N_EDGES + e];
        int slot = atomicAdd(&cur[d], 1);
        ssrc[slot] = ei[e];
    }
}

// ---------------------------------------------------------------------------
// P1: per-chunk partial sums. 32 chunks of 16 ranks. For chunk c, col j:
//   PbA/PbB: masked base-set partials over k in [16c,16c+16) (natural order)
//   SA/SB:   sorted-rank chunk sums (sgn*w, sgn*b weighted W2 rows)
// Grid 64 = 32 chunks x 2 j-chunks of 256.
// ---------------------------------------------------------------------------
__global__ void p1_chunks(const float* __restrict__ W1, const float* __restrict__ b1,
                          const float* __restrict__ W2, const int* __restrict__ ksort,
                          float* __restrict__ PbA, float* __restrict__ PbB,
                          float* __restrict__ SA, float* __restrict__ SB) {
    int c = blockIdx.x & 31;
    int jc = blockIdx.x >> 5;
    int j = jc * 256 + threadIdx.x;
    float ba = 0.0f, bb = 0.0f, sa = 0.0f, sb = 0.0f;
#pragma unroll 4
    for (int s = 0; s < 16; ++s) {
        int k = c * 16 + s;
        float w = W1[k], b = b1[k];
        bool act = (w < 0.0f) || (w == 0.0f && b > 0.0f);
        if (act) {
            float w2 = W2[k * 512 + j];
            ba = fmaf(w, w2, ba);
            bb = fmaf(b, w2, bb);
        }
        int kr = ksort[c * 16 + s];
        float wr = W1[kr], br = b1[kr];
        float sgn = (wr > 0.0f) ? 1.0f : ((wr < 0.0f) ? -1.0f : 0.0f);
        float w2r = W2[kr * 512 + j];
        sa = fmaf(sgn * wr, w2r, sa);
        sb = fmaf(sgn * br, w2r, sb);
    }
    PbA[c * 512 + j] = ba; PbB[c * 512 + j] = bb;
    SA[c * 512 + j] = sa;  SB[c * 512 + j] = sb;
}

// ---------------------------------------------------------------------------
// P2: per-column scan over the 32 chunks. base = sum of masked partials;
// then exclusive prefix of SA/SB (+base) written back over PbA/PbB.
// 2 blocks x 256.
// ---------------------------------------------------------------------------
__global__ void p2_prefix(float* __restrict__ PbA, float* __restrict__ PbB,
                          const float* __restrict__ SA, const float* __restrict__ SB) {
    int j = blockIdx.x * 256 + threadIdx.x;
    float bA = 0.0f, bB = 0.0f;
#pragma unroll
    for (int c = 0; c < 32; ++c) { bA += PbA[c * 512 + j]; bB += PbB[c * 512 + j]; }
    float rA = bA, rB = bB;
#pragma unroll
    for (int c = 0; c < 32; ++c) {
        float sA = SA[c * 512 + j], sB = SB[c * 512 + j];
        PbA[c * 512 + j] = rA;
        PbB[c * 512 + j] = rB;
        rA += sA; rB += sB;
    }
}

// ---------------------------------------------------------------------------
// P3: emit A[513][512], B2[513][512]. Chunk c starts from scanned prefix
// PA[c][j] and walks its 16 ranks. Chunk 31 also emits row 512.
// Grid 64 = 32 chunks x 2 j-chunks.
// ---------------------------------------------------------------------------
__global__ void p3_emit(const float* __restrict__ W1, const float* __restrict__ b1,
                        const float* __restrict__ b2, const float* __restrict__ W2,
                        const int* __restrict__ ksort,
                        const float* __restrict__ PA, const float* __restrict__ PB,
                        float* __restrict__ A, float* __restrict__ B2t) {
    int c = blockIdx.x & 31;
    int jc = blockIdx.x >> 5;
    int j = jc * 256 + threadIdx.x;
    float runA = PA[c * 512 + j], runB = PB[c * 512 + j];
    float bb2 = b2[j];
#pragma unroll 4
    for (int s = 0; s < 16; ++s) {
        int m = c * 16 + s;
        A[m * 512 + j]   = runA;
        B2t[m * 512 + j] = runB + bb2;
        int k = ksort[m];
        float w = W1[k], b = b1[k];
        float sgn = (w > 0.0f) ? 1.0f : ((w < 0.0f) ? -1.0f : 0.0f);
        float w2 = W2[k * 512 + j];
        runA = fmaf(sgn * w, w2, runA);
        runB = fmaf(sgn * b, w2, runB);
    }
    if (c == 31) {
        A[512 * 512 + j]   = runA;
        B2t[512 * 512 + j] = runB + bb2;
    }
}

// ---------------------------------------------------------------------------
// K3: per-edge message. 32 lanes per edge (o = lane). Binary-search interval m,
// msg[o] = a*(x_src . A_m[:,o]) + (x_src . B2_m[:,o]); atomic scatter to dst.
// ---------------------------------------------------------------------------
__global__ void k3_edges(const float* __restrict__ x, const float* __restrict__ ea,
                         const int* __restrict__ ei,
                         const float* __restrict__ A, const float* __restrict__ B2t,
                         const float* __restrict__ tsort,
                         float* __restrict__ summed) {
    __shared__ float ts[512];
    for (int i = threadIdx.x; i < 512; i += blockDim.x) ts[i] = tsort[i];
    __syncthreads();
    int gid = blockIdx.x * blockDim.x + threadIdx.x;
    int lane = gid & 31;
    int e = gid >> 5;
    if (e >= N_EDGES) return;
    float a = ea[e];
    int s = ei[e], d = ei[N_EDGES + e];
    // m = #{t_r < a}
    int lo = 0, hi = 512;
    while (lo < hi) {
        int mid = (lo + hi) >> 1;
        if (ts[mid] < a) lo = mid + 1; else hi = mid;
    }
    int m = lo;
    float xv = (lane < 16) ? x[s * 16 + lane] : 0.0f;
    const float* Ar = A   + m * 512;
    const float* Br = B2t + m * 512;
    float xa = 0.0f, xb = 0.0f;
#pragma unroll
    for (int i = 0; i < 16; ++i) {
        float xi = __shfl(xv, i, 32);
        xa = fmaf(xi, Ar[i * 32 + lane], xa);
        xb = fmaf(xi, Br[i * 32 + lane], xb);
    }
    float msg = fmaf(a, xa, xb);
    atomicAdd(&summed[d * 32 + lane], msg);
}

// ---------------------------------------------------------------------------
// K4: per-node: aggr = summed/max(cnt,1); h1 = relu(aggr + x@root + bias1);
// xw = h1@Wg; dinv = rsqrt(indeg + 1). cnt = offs[n+1]-offs[n].
// ---------------------------------------------------------------------------
__global__ void k4_nodes(const float* __restrict__ x, const float* __restrict__ summed,
                         const int* __restrict__ offs,
                         const float* __restrict__ root, const float* __restrict__ bias1,
                         const float* __restrict__ Wg,
                         float* __restrict__ xw, float* __restrict__ dinv) {
    __shared__ float sroot[512], sb1[32], swg[320];
    for (int i = threadIdx.x; i < 512; i += blockDim.x) sroot[i] = root[i];
    for (int i = threadIdx.x; i < 32; i += blockDim.x) sb1[i] = bias1[i];
    for (int i = threadIdx.x; i < 320; i += blockDim.x) swg[i] = Wg[i];
    __syncthreads();
    int n = blockIdx.x * blockDim.x + threadIdx.x;
    if (n >= N_NODES) return;
    float c = (float)(offs[n + 1] - offs[n]);
    float inv = 1.0f / fmaxf(c, 1.0f);
    float xr[16];
#pragma unroll
    for (int i = 0; i < 16; ++i) xr[i] = x[n * 16 + i];
    float acc[10];
#pragma unroll
    for (int cc = 0; cc < 10; ++cc) acc[cc] = 0.0f;
#pragma unroll
    for (int o = 0; o < 32; ++o) {
        float h = summed[n * 32 + o] * inv + sb1[o];
#pragma unroll
        for (int i = 0; i < 16; ++i) h = fmaf(xr[i], sroot[i * 32 + o], h);
        h = fmaxf(h, 0.0f);
#pragma unroll
        for (int cc = 0; cc < 10; ++cc) acc[cc] = fmaf(h, swg[o * 10 + cc], acc[cc]);
    }
#pragma unroll
    for (int cc = 0; cc < 10; ++cc) xw[n * 10 + cc] = acc[cc];
    dinv[n] = rsqrtf(c + 1.0f);
}

// ---------------------------------------------------------------------------
// K56: fused GCN gather + self-loop + bias + log_softmax -> d_out.
// One thread per node; in-edges via CSR (no atomics).
// ---------------------------------------------------------------------------
__global__ void k56_final(const int* __restrict__ offs, const int* __restrict__ ssrc,
                          const float* __restrict__ xw, const float* __restrict__ dinv,
                          const float* __restrict__ bg, float* __restrict__ out) {
    __shared__ float sbg[16];
    if (threadIdx.x < 10) sbg[threadIdx.x] = bg[threadIdx.x];
    __syncthreads();
    int n = blockIdx.x * blockDim.x + threadIdx.x;
    if (n >= N_NODES) return;
    float dn = dinv[n];
    float d2 = dn * dn;
    float acc[10];
#pragma unroll
    for (int c = 0; c < 10; ++c) acc[c] = fmaf(xw[n * 10 + c], d2, sbg[c]);
    int s0 = offs[n], s1 = offs[n + 1];
    for (int sl = s0; sl < s1; ++sl) {
        int s = ssrc[sl];
        float nf = dinv[s] * dn;
#pragma unroll
        for (int c = 0; c < 10; ++c) acc[c] = fmaf(xw[s * 10 + c], nf, acc[c]);
    }
    float mx = -1e30f;
#pragma unroll
    for (int c = 0; c < 10; ++c) mx = fmaxf(mx, acc[c]);
    float se = 0.0f;
#pragma unroll
    for (int c = 0; c < 10; ++c) se += expf(acc[c] - mx);
    float lse = logf(se) + mx;
#pragma unroll
    for (int c = 0; c < 10; ++c) out[n * 10 + c] = acc[c] - lse;
}

// ---------------------------------------------------------------------------
extern "C" void kernel_launch(void* const* d_in, const int* in_sizes, int n_in,
                              void* d_out, int out_size, void* d_ws, size_t ws_size,
                              hipStream_t stream) {
    const float* x     = (const float*)d_in[0];
    const float* ea    = (const float*)d_in[1];
    const float* W1    = (const float*)d_in[2];
    const float* b1    = (const float*)d_in[3];
    const float* W2    = (const float*)d_in[4];
    const float* b2    = (const float*)d_in[5];
    const float* root  = (const float*)d_in[6];
    const float* bias1 = (const float*)d_in[7];
    const float* Wg    = (const float*)d_in[8];
    const float* bg    = (const float*)d_in[9];
    const int*   ei    = (const int*)d_in[10];
    float* out = (float*)d_out;

    // workspace layout (4-byte elems):
    //   A[513*512] | B2[513*512] | tsort[512] | ksort[512]
    //   | summed[N*32] | deg[N]   (<- zeroed region, contiguous)
    //   | offs[N+1] | cur[N] | ssrc[E] | xw[N*10] | dinv[N]
    //   | PbA[32*512] | PbB[32*512] | SA[32*512] | SB[32*512]
    float* A      = (float*)d_ws;
    float* B2t    = A + 513 * 512;
    float* tsort  = B2t + 513 * 512;
    int*   ksort  = (int*)(tsort + 512);
    float* summed = (float*)(ksort + 512);
    int*   deg    = (int*)(summed + N_NODES * 32);
    int*   offs   = deg + N_NODES;
    int*   cur    = offs + N_NODES + 1;
    int*   ssrc   = cur + N_NODES;
    float* xw     = (float*)(ssrc + N_EDGES);
    float* dinv   = xw + N_NODES * 10;
    float* PbA    = dinv + N_NODES;
    float* PbB    = PbA + 32 * 512;
    float* SA     = PbB + 32 * 512;
    float* SB     = SA + 32 * 512;

    k0_zero<<<1024, 256, 0, stream>>>(summed, N_NODES * 33);
    k1_sort<<<1, 512, 0, stream>>>(W1, b1, tsort, ksort);
    kb1_deg<<<(N_EDGES + 255) / 256, 256, 0, stream>>>(ei, deg);
    s_scan<<<1, 1024, 0, stream>>>(deg, offs, cur);
    kb3_fill<<<(N_EDGES + 255) / 256, 256, 0, stream>>>(ei, cur, ssrc);
    p1_chunks<<<64, 256, 0, stream>>>(W1, b1, W2, ksort, PbA, PbB, SA, SB);
    p2_prefix<<<2, 256, 0, stream>>>(PbA, PbB, SA, SB);
    p3_emit<<<64, 256, 0, stream>>>(W1, b1, b2, W2, ksort, PbA, PbB, A, B2t);
    k3_edges<<<(N_EDGES * 32 + 255) / 256, 256, 0, stream>>>(x, ea, ei, A, B2t, tsort,
                                                             summed);
    k4_nodes<<<(N_NODES + 255) / 256, 256, 0, stream>>>(x, summed, offs, root, bias1,
                                                        Wg, xw, dinv);
    k56_final<<<(N_NODES + 255) / 256, 256, 0, stream>>>(offs, ssrc, xw, dinv, bg, out);
}